// Round 1
// baseline (277.387 us; speedup 1.0000x reference)
//
#include <hip/hip_runtime.h>

// Problem constants
#define B_  64
#define S_  512
#define D_  768
#define H_  768
#define C_  5
#define M_  (B_ * S_)        // 32768 rows

typedef float f32x4 __attribute__((ext_vector_type(4)));
typedef short short8 __attribute__((ext_vector_type(8)));   // bf16x8 MFMA operand

#define W1T_ELEMS (D_ * H_)      // 589824  (bf16: 1.18 MB)
#define XBF_ELEMS (M_ * D_)      // 25165824 (bf16: 50.33 MB)

// prep_all grid partition
#define PX_BLOCKS   (XBF_ELEMS / (256 * 8))          // 12288
#define PW_BLOCKS   ((D_ / 32) * (H_ / 32))          // 576
#define PI_BLOCKS   ((M_ * C_ + 255) / 256)          // 640

__device__ __forceinline__ unsigned short f2bf(float f) {
    unsigned int u = __float_as_uint(f);
    u += 0x7FFFu + ((u >> 16) & 1u);     // RNE
    return (unsigned short)(u >> 16);
}

// =========================================================================
// Kernel 1: fused prep — prep_x | prep_w1 | init_pot in one dispatch
// =========================================================================
__global__ __launch_bounds__(256) void prep_all_kernel(
    const float* __restrict__ X, const float* __restrict__ W1,
    const float* __restrict__ b2, const float* __restrict__ lb,
    const float* __restrict__ rb,
    unsigned short* __restrict__ xbf, unsigned short* __restrict__ w1t,
    float* __restrict__ pot)
{
    __shared__ float t[32][33];
    const int bid = blockIdx.x;
    const int tid = threadIdx.x;

    if (bid < PX_BLOCKS) {
        // ---- X fp32 -> bf16 ----
        const size_t i0 = ((size_t)bid * 256 + tid) * 8;
        const float4 a = *(const float4*)(X + i0);
        const float4 b = *(const float4*)(X + i0 + 4);
        union { unsigned short u[8]; uint4 v; } o;
        o.u[0] = f2bf(a.x); o.u[1] = f2bf(a.y); o.u[2] = f2bf(a.z); o.u[3] = f2bf(a.w);
        o.u[4] = f2bf(b.x); o.u[5] = f2bf(b.y); o.u[6] = f2bf(b.z); o.u[7] = f2bf(b.w);
        *(uint4*)(xbf + i0) = o.v;
    } else if (bid < PX_BLOCKS + PW_BLOCKS) {
        // ---- W1 [k][n] fp32 -> w1t [n][k] bf16 (LDS-tiled transpose) ----
        const int b2i = bid - PX_BLOCKS;
        const int bx = b2i % (H_ / 32);       // n tile
        const int by = b2i / (H_ / 32);       // k tile
        const int lx = tid & 31, ly = tid >> 5;
        #pragma unroll
        for (int j = 0; j < 4; ++j)
            t[ly + 8 * j][lx] = W1[(by * 32 + ly + 8 * j) * H_ + bx * 32 + lx];
        __syncthreads();
        #pragma unroll
        for (int j = 0; j < 4; ++j)
            w1t[(size_t)(bx * 32 + ly + 8 * j) * D_ + by * 32 + lx] = f2bf(t[lx][ly + 8 * j]);
    } else {
        // ---- pot = b2 + boundaries ----
        const int idx = (bid - PX_BLOCKS - PW_BLOCKS) * 256 + tid;
        if (idx < M_ * C_) {
            const int c = idx % C_;
            const int tt = (idx / C_) & (S_ - 1);
            float v = b2[c];
            if (tt == 0)      v += lb[c];
            if (tt == S_ - 1) v += rb[c];
            pot[idx] = v;
        }
    }
}

// standalone prep_w1 for the fallback branch only
__global__ __launch_bounds__(256) void prep_w1_kernel(
    const float* __restrict__ W1, unsigned short* __restrict__ w1t)
{
    __shared__ float t[32][33];
    const int bx = blockIdx.x, by = blockIdx.y;
    const int lx = threadIdx.x & 31, ly = threadIdx.x >> 5;
    #pragma unroll
    for (int j = 0; j < 4; ++j)
        t[ly + 8 * j][lx] = W1[(by * 32 + ly + 8 * j) * H_ + bx * 32 + lx];
    __syncthreads();
    #pragma unroll
    for (int j = 0; j < 4; ++j)
        w1t[(size_t)(bx * 32 + ly + 8 * j) * D_ + by * 32 + lx] = f2bf(t[lx][ly + 8 * j]);
}

__global__ __launch_bounds__(256) void init_pot_kernel(
    const float* __restrict__ b2, const float* __restrict__ lb,
    const float* __restrict__ rb, float* __restrict__ pot)
{
    const int idx = blockIdx.x * 256 + threadIdx.x;
    if (idx < M_ * C_) {
        const int c = idx % C_;
        const int t = (idx / C_) & (S_ - 1);
        float v = b2[c];
        if (t == 0)      v += lb[c];
        if (t == S_ - 1) v += rb[c];
        pot[idx] = v;
    }
}

// =========================================================================
// Kernel 2: 256x256-tile, 4-phase-per-K-tile (8-phase/2-tiles) bf16 MFMA
// GEMM with counted vmcnt (T3+T4) and setprio-wrapped MFMA clusters (T5).
//
// Schedule (derived, per K-tile k; CUR = k&1; one half-tile staged/phase):
//   ph1: ds_read A-lo,B-lo(k)  | stage B-lo(k+1)->buf[k+1&1] | BAR | 16 MFMA | BAR
//   ph2: ds_read B-hi(k)       | stage A-lo(k+2)->buf[k&1]   | BAR | 16 MFMA | BAR
//   ph3: ds_read A-hi(k)       | stage B-hi(k+2)->buf[k&1]   | BAR | 16 MFMA | BAR
//   ph4:                       | stage A-hi(k+2)->buf[k&1]   | BAR | 16 MFMA
//        | s_waitcnt vmcnt(6)  (newest 3 halves of tile k+2 stay in flight;
//          everything older — i.e. ALL of tile k+1 — is guaranteed landed) | BAR
// Region safety: each stage overwrites a region whose last ds_read was in
// the previous phase, separated by a barrier (reads complete before the
// consuming MFMA, which precedes that barrier). B-lo is kept in registers
// so ph4 needs no ds_read. Tail: k=10 uses vmcnt(0), k=11 stages nothing —
// counted waits never under-guard. LDS lane-major layout: conflict-free
// (measured 0) and matches global_load_lds' linear wave-uniform dest.
// =========================================================================
__device__ __forceinline__ void gload16(const void* g, void* l) {
    __builtin_amdgcn_global_load_lds(
        (const __attribute__((address_space(1))) unsigned int*)g,
        (__attribute__((address_space(3))) unsigned int*)l, 16, 0, 0);
}

#define KT_ (D_ / 64)   // 12 K-tiles

#define PH_BAR() do { \
    __builtin_amdgcn_sched_barrier(0); \
    __builtin_amdgcn_s_barrier(); \
    __builtin_amdgcn_sched_barrier(0); \
} while (0)

// stage one half-tile (128 rows x 64 cols bf16): 2 x global_load_lds_dwordx4/wave
#define STG_A(BUF, KI, HH) do { \
    gload16(aSrc + (size_t)(HH) * 128 * D_ + (KI) * 64,      &Alds[BUF][(((HH) * 8 + w) * 2 + 0) * 512]); \
    gload16(aSrc + (size_t)(HH) * 128 * D_ + (KI) * 64 + 32, &Alds[BUF][(((HH) * 8 + w) * 2 + 1) * 512]); \
} while (0)
#define STG_B(BUF, KI, HH) do { \
    gload16(bSrc + (size_t)(HH) * 128 * D_ + (KI) * 64,      &Blds[BUF][(((HH) * 8 + w) * 2 + 0) * 512]); \
    gload16(bSrc + (size_t)(HH) * 128 * D_ + (KI) * 64 + 32, &Blds[BUF][(((HH) * 8 + w) * 2 + 1) * 512]); \
} while (0)

// fragment reads: group g16 in [0,16), kk in {0,1}; contiguous 16B/lane
#define LDA(CUR, G16, KK) (*(const short8*)&Alds[CUR][((G16) * 2 + (KK)) * 512 + lane * 8])
#define LDB(CUR, G16, KK) (*(const short8*)&Blds[CUR][((G16) * 2 + (KK)) * 512 + lane * 8])

// one C-quadrant x K=64: 16 MFMA; kk outermost so dependent pairs are 8 apart
#define MFMA_Q(MH, NH, BR) do { \
    __builtin_amdgcn_s_setprio(1); \
    _Pragma("unroll") \
    for (int kk = 0; kk < 2; ++kk) \
        _Pragma("unroll") \
        for (int n2 = 0; n2 < 2; ++n2) \
            _Pragma("unroll") \
            for (int m2 = 0; m2 < 4; ++m2) \
                acc[(MH) * 4 + m2][(NH) * 2 + n2] = __builtin_amdgcn_mfma_f32_16x16x32_bf16( \
                    af[m2][kk], BR[n2][kk], acc[(MH) * 4 + m2][(NH) * 2 + n2], 0, 0, 0); \
    __builtin_amdgcn_s_setprio(0); \
} while (0)

#define TILE_BODY(KI, CUR, NXT, DO_S1, DO_S2, VMODE) do { \
    /* ---- phase 1: read A-lo + B-lo, stage B-lo(k+1) ---- */ \
    _Pragma("unroll") \
    for (int m2 = 0; m2 < 4; ++m2) { \
        af[m2][0] = LDA(CUR, wm * 8 + m2, 0); \
        af[m2][1] = LDA(CUR, wm * 8 + m2, 1); \
    } \
    _Pragma("unroll") \
    for (int n2 = 0; n2 < 2; ++n2) { \
        blo[n2][0] = LDB(CUR, wn * 4 + n2, 0); \
        blo[n2][1] = LDB(CUR, wn * 4 + n2, 1); \
    } \
    if (DO_S1) { STG_B(NXT, (KI) + 1, 0); } \
    PH_BAR(); \
    MFMA_Q(0, 0, blo); \
    PH_BAR(); \
    /* ---- phase 2: read B-hi, stage A-lo(k+2) ---- */ \
    _Pragma("unroll") \
    for (int n2 = 0; n2 < 2; ++n2) { \
        bhi[n2][0] = LDB(CUR, wn * 4 + 2 + n2, 0); \
        bhi[n2][1] = LDB(CUR, wn * 4 + 2 + n2, 1); \
    } \
    if (DO_S2) { STG_A(CUR, (KI) + 2, 0); } \
    PH_BAR(); \
    MFMA_Q(0, 1, bhi); \
    PH_BAR(); \
    /* ---- phase 3: read A-hi, stage B-hi(k+2) ---- */ \
    _Pragma("unroll") \
    for (int m2 = 0; m2 < 4; ++m2) { \
        af[m2][0] = LDA(CUR, wm * 8 + 4 + m2, 0); \
        af[m2][1] = LDA(CUR, wm * 8 + 4 + m2, 1); \
    } \
    if (DO_S2) { STG_B(CUR, (KI) + 2, 1); } \
    PH_BAR(); \
    MFMA_Q(1, 1, bhi); \
    PH_BAR(); \
    /* ---- phase 4: stage A-hi(k+2), MFMA, counted wait ---- */ \
    if (DO_S2) { STG_A(CUR, (KI) + 2, 1); } \
    PH_BAR(); \
    MFMA_Q(1, 0, blo); \
    if ((VMODE) == 6) { asm volatile("s_waitcnt vmcnt(6)" ::: "memory"); } \
    else if ((VMODE) == 0) { asm volatile("s_waitcnt vmcnt(0)" ::: "memory"); } \
    PH_BAR(); \
} while (0)

__global__ __launch_bounds__(512) void gemm_256_kernel(
    const unsigned short* __restrict__ xbf,   // [M_, D_] bf16
    const unsigned short* __restrict__ w1t,   // [H_, D_] bf16 (n-major)
    const float* __restrict__ b1,
    const float* __restrict__ W2,             // [H_, C_]
    float* __restrict__ pot)                  // [M_, C_] pre-initialized
{
    // per buf per matrix: 256 rows x 64 cols bf16 = 16384 shorts = 32 KB
    __shared__ __align__(16) unsigned short Alds[2][16384];   // 64 KB
    __shared__ __align__(16) unsigned short Blds[2][16384];   // 64 KB (total 128 KB)

    const int tid  = threadIdx.x;
    const int lane = tid & 63;
    const int w    = tid >> 6;          // wave 0..7
    const int wm   = w >> 2;            // M half   (rows wm*128..+127)
    const int wn   = w & 3;             // N quarter (cols wn*64..+63)
    const int i15  = lane & 15, quad = lane >> 4;

    // XCD-aware bijective swizzle: 384 = 8 XCD x 48; n fastest within a chunk
    const int bid  = blockIdx.x;
    const int wgid = (bid & 7) * 48 + (bid >> 3);
    const int nb   = wgid % 3, mb = wgid / 3;
    const int m0   = mb * 256, n0 = nb * 256;

    // per-lane global staging sources (wave w owns row-group w of each half)
    const unsigned short* aSrc = xbf + (size_t)(m0 + w * 16 + i15) * D_ + quad * 8;
    const unsigned short* bSrc = w1t + (size_t)(n0 + w * 16 + i15) * D_ + quad * 8;

    f32x4 acc[8][4];
    #pragma unroll
    for (int mi = 0; mi < 8; ++mi)
        #pragma unroll
        for (int ni = 0; ni < 4; ++ni)
            acc[mi][ni] = (f32x4){0.f, 0.f, 0.f, 0.f};

    short8 af[4][2], blo[2][2], bhi[2][2];

    // ---- prologue: tile0 fully + tile1's {A-lo, B-hi, A-hi} (B-lo(1) at 0.ph1)
    STG_B(0, 0, 0);
    STG_A(0, 0, 0);
    STG_B(0, 0, 1);
    STG_A(0, 0, 1);
    STG_A(1, 1, 0);
    STG_B(1, 1, 1);
    STG_A(1, 1, 1);
    asm volatile("s_waitcnt vmcnt(6)" ::: "memory");   // tile0's 4 halves landed
    PH_BAR();

    // ---- main loop: tiles 0..9 full schedule ----
    for (int k = 0; k < 10; k += 2) {
        TILE_BODY(k,     0, 1, 1, 1, 6);
        TILE_BODY(k + 1, 1, 0, 1, 1, 6);
    }
    // ---- tail: tile 10 (stage B-lo(11) only, drain), tile 11 (no stages) ----
    TILE_BODY(10, 0, 1, 1, 0, 0);
    TILE_BODY(11, 1, 0, 0, 0, 2);

    // ---- epilogue: relu(h+b1)@W2, wave-partial -> LDS -> block atomics ----
    // pp aliases Alds (last read was tile 10; all LDS reads & gloads drained)
    float* pp = (float*)&Alds[0][0];          // [4 wn][256 rows][C_] = 20 KB

    float b1v[4], w2v[4][C_];
    #pragma unroll
    for (int ni = 0; ni < 4; ++ni) {
        const int col = n0 + wn * 64 + ni * 16 + i15;
        b1v[ni] = b1[col];
        #pragma unroll
        for (int cc = 0; cc < C_; ++cc) w2v[ni][cc] = W2[col * C_ + cc];
    }

    #pragma unroll
    for (int mi = 0; mi < 8; ++mi) {
        float ps[4][C_];
        #pragma unroll
        for (int r = 0; r < 4; ++r)
            #pragma unroll
            for (int cc = 0; cc < C_; ++cc) ps[r][cc] = 0.f;

        #pragma unroll
        for (int ni = 0; ni < 4; ++ni)
            #pragma unroll
            for (int r = 0; r < 4; ++r) {
                float h = acc[mi][ni][r] + b1v[ni];
                h = h > 0.f ? h : 0.f;
                #pragma unroll
                for (int cc = 0; cc < C_; ++cc)
                    ps[r][cc] = fmaf(h, w2v[ni][cc], ps[r][cc]);
            }

        #pragma unroll
        for (int off = 1; off < 16; off <<= 1)
            #pragma unroll
            for (int r = 0; r < 4; ++r)
                #pragma unroll
                for (int cc = 0; cc < C_; ++cc)
                    ps[r][cc] += __shfl_xor(ps[r][cc], off, 64);

        if (i15 == 0) {
            #pragma unroll
            for (int r = 0; r < 4; ++r) {
                const int row = wm * 128 + mi * 16 + quad * 4 + r;
                #pragma unroll
                for (int cc = 0; cc < C_; ++cc)
                    pp[(wn * 256 + row) * C_ + cc] = ps[r][cc];
            }
        }
    }
    __syncthreads();

    for (int idx = tid; idx < 256 * C_; idx += 512) {
        atomicAdd(&pot[(size_t)m0 * C_ + idx],
                  pp[idx] + pp[256 * C_ + idx] + pp[2 * 256 * C_ + idx] + pp[3 * 256 * C_ + idx]);
    }
}

// =========================================================================
// Mid fallback (R3 kernel, proven): bf16 B from ws, fp32 A via LDS
// =========================================================================
__global__ __launch_bounds__(256) void gemm_bf16_kernel(
    const float* __restrict__ X,
    const unsigned short* __restrict__ w1t,
    const float* __restrict__ b1,
    const float* __restrict__ W2,
    float* __restrict__ pot)
{
    __shared__ __align__(16) float          Asm[128 * 32];
    __shared__ __align__(16) unsigned short Bsm[128 * 32];
    __shared__ float pp[2][128][C_];

    const int tid  = threadIdx.x;
    const int lane = tid & 63, w = tid >> 6;
    const int wm   = w >> 1, wn = w & 1;
    const int i15  = lane & 15, quad = lane >> 4;

    const int bid = blockIdx.x;
    const int r8 = bid & 7, q8 = bid >> 3;
    const int nb = q8 % 6, mhi = q8 / 6;
    const int m0 = (mhi * 8 + r8) * 128;
    const int n0 = nb * 128;

    const float* gA[4];
    float* lA[4];
    const unsigned short* gB[2];
    unsigned short* lB[2];
    #pragma unroll
    for (int i = 0; i < 4; ++i) {
        const int a = 4 * w + i, g = a >> 1, h = a & 1;
        gA[i] = X + (size_t)(m0 + g * 16 + i15) * D_ + (4 * h + quad) * 4;
        lA[i] = &Asm[g * 512 + h * 256];
    }
    #pragma unroll
    for (int i = 0; i < 2; ++i) {
        const int b = 2 * w + i;
        gB[i] = w1t + (size_t)(n0 + b * 16 + i15) * D_ + quad * 8;
        lB[i] = &Bsm[b * 512];
    }

    f32x4 acc[4][4];
    #pragma unroll
    for (int mi = 0; mi < 4; ++mi)
        #pragma unroll
        for (int ni = 0; ni < 4; ++ni)
            acc[mi][ni] = (f32x4){0.f, 0.f, 0.f, 0.f};

    for (int kt = 0; kt < D_ / 32; ++kt) {
        __syncthreads();
        #pragma unroll
        for (int i = 0; i < 4; ++i) { gload16(gA[i], lA[i]); gA[i] += 32; }
        #pragma unroll
        for (int i = 0; i < 2; ++i) { gload16(gB[i], lB[i]); gB[i] += 32; }
        __syncthreads();

        short8 af[4];
        #pragma unroll
        for (int mi = 0; mi < 4; ++mi) {
            const int row = wm * 64 + mi * 16 + i15;
            const int base = (row >> 4) * 512 + (row & 15) * 4 + quad * 128;
            const f32x4 lo = *(const f32x4*)&Asm[base];
            const f32x4 hi = *(const f32x4*)&Asm[base + 64];
            float f[8];
            *(f32x4*)&f[0] = lo; *(f32x4*)&f[4] = hi;
            union { short8 s; unsigned short u[8]; } cv;
            #pragma unroll
            for (int j = 0; j < 8; ++j) cv.u[j] = f2bf(f[j]);
            af[mi] = cv.s;
        }
        short8 bfr[4];
        #pragma unroll
        for (int ni = 0; ni < 4; ++ni) {
            const int row = wn * 64 + ni * 16 + i15;
            bfr[ni] = *(const short8*)&Bsm[(row >> 4) * 512 + quad * 128 + (row & 15) * 8];
        }
        #pragma unroll
        for (int ni = 0; ni < 4; ++ni)
            #pragma unroll
            for (int mi = 0; mi < 4; ++mi)
                acc[mi][ni] = __builtin_amdgcn_mfma_f32_16x16x32_bf16(
                    af[mi], bfr[ni], acc[mi][ni], 0, 0, 0);
    }

    float b1v[4], w2v[4][C_];
    #pragma unroll
    for (int ni = 0; ni < 4; ++ni) {
        const int col = n0 + wn * 64 + ni * 16 + i15;
        b1v[ni] = b1[col];
        #pragma unroll
        for (int cc = 0; cc < C_; ++cc) w2v[ni][cc] = W2[col * C_ + cc];
    }

    #pragma unroll
    for (int mi = 0; mi < 4; ++mi) {
        float ps[4][C_];
        #pragma unroll
        for (int r = 0; r < 4; ++r)
            #pragma unroll
            for (int cc = 0; cc < C_; ++cc) ps[r][cc] = 0.f;

        #pragma unroll
        for (int ni = 0; ni < 4; ++ni)
            #pragma unroll
            for (int r = 0; r < 4; ++r) {
                float h = acc[mi][ni][r] + b1v[ni];
                h = h > 0.f ? h : 0.f;
                #pragma unroll
                for (int cc = 0; cc < C_; ++cc)
                    ps[r][cc] = fmaf(h, w2v[ni][cc], ps[r][cc]);
            }

        #pragma unroll
        for (int off = 1; off < 16; off <<= 1)
            #pragma unroll
            for (int r = 0; r < 4; ++r)
                #pragma unroll
                for (int cc = 0; cc < C_; ++cc)
                    ps[r][cc] += __shfl_xor(ps[r][cc], off, 64);

        if (i15 == 0) {
            #pragma unroll
            for (int r = 0; r < 4; ++r) {
                const int row = wm * 64 + mi * 16 + quad * 4 + r;
                #pragma unroll
                for (int cc = 0; cc < C_; ++cc)
                    pp[wn][row][cc] = ps[r][cc];
            }
        }
    }
    __syncthreads();

    for (int idx = tid; idx < 128 * C_; idx += 256) {
        const int row = idx / C_, cc = idx % C_;
        atomicAdd(&pot[(size_t)(m0 + row) * C_ + cc],
                  pp[0][row][cc] + pp[1][row][cc]);
    }
}

// =========================================================================
// Last-resort fp32 GEMM (R1 kernel, proven) if ws < 1.18 MB
// =========================================================================
#define FBK 8
#define FLDS 132
__global__ __launch_bounds__(256) void gemm_relu_pot_kernel(
    const float* __restrict__ X, const float* __restrict__ W1,
    const float* __restrict__ b1, const float* __restrict__ W2,
    float* __restrict__ pot)
{
    __shared__ float As[FBK * FLDS];
    __shared__ float Bs[FBK * FLDS];
    __shared__ float w2s[128][C_];

    const int tid = threadIdx.x;
    const int tx = tid & 15, ty = tid >> 4;
    const int m0 = blockIdx.y * 128, n0 = blockIdx.x * 128;

    for (int idx = tid; idx < 128 * C_; idx += 256)
        w2s[idx / C_][idx % C_] = W2[(n0 + idx / C_) * C_ + idx % C_];

    float acc[2][2][4][4];
    #pragma unroll
    for (int a = 0; a < 2; ++a)
        #pragma unroll
        for (int b = 0; b < 2; ++b)
            #pragma unroll
            for (int i = 0; i < 4; ++i)
                #pragma unroll
                for (int j = 0; j < 4; ++j) acc[a][b][i][j] = 0.f;

    const int arow = tid >> 1, aq = tid & 1;
    const int brow = tid >> 5, bq = tid & 31;
    const float* Aptr = X + (m0 + arow) * D_ + aq * 4;
    const float* Bptr = W1 + brow * H_ + n0 + bq * 4;

    for (int kt = 0; kt < D_; kt += FBK) {
        const float4 avv = *(const float4*)Aptr;
        const float4 bvv = *(const float4*)Bptr;
        __syncthreads();
        As[(aq * 4 + 0) * FLDS + arow] = avv.x;
        As[(aq * 4 + 1) * FLDS + arow] = avv.y;
        As[(aq * 4 + 2) * FLDS + arow] = avv.z;
        As[(aq * 4 + 3) * FLDS + arow] = avv.w;
        *(float4*)&Bs[brow * FLDS + bq * 4] = bvv;
        __syncthreads();
        #pragma unroll
        for (int k = 0; k < FBK; ++k) {
            const float4 a0 = *(const float4*)&As[k * FLDS + (ty << 2)];
            const float4 a1 = *(const float4*)&As[k * FLDS + 64 + (ty << 2)];
            const float4 b0 = *(const float4*)&Bs[k * FLDS + (tx << 2)];
            const float4 b1r = *(const float4*)&Bs[k * FLDS + 64 + (tx << 2)];
            const float ar[2][4] = {{a0.x,a0.y,a0.z,a0.w},{a1.x,a1.y,a1.z,a1.w}};
            const float br[2][4] = {{b0.x,b0.y,b0.z,b0.w},{b1r.x,b1r.y,b1r.z,b1r.w}};
            #pragma unroll
            for (int ri = 0; ri < 2; ++ri)
                #pragma unroll
                for (int i = 0; i < 4; ++i)
                    #pragma unroll
                    for (int rj = 0; rj < 2; ++rj)
                        #pragma unroll
                        for (int j = 0; j < 4; ++j)
                            acc[ri][rj][i][j] = fmaf(ar[ri][i], br[rj][j], acc[ri][rj][i][j]);
        }
        Aptr += FBK;
        Bptr += FBK * H_;
    }

    float ps[2][4][C_];
    #pragma unroll
    for (int ri = 0; ri < 2; ++ri)
        #pragma unroll
        for (int i = 0; i < 4; ++i)
            #pragma unroll
            for (int cc = 0; cc < C_; ++cc) ps[ri][i][cc] = 0.f;

    #pragma unroll
    for (int rj = 0; rj < 2; ++rj)
        #pragma unroll
        for (int j = 0; j < 4; ++j) {
            const int nl = rj * 64 + (tx << 2) + j;
            const float bj = b1[n0 + nl];
            float w2c[C_];
            #pragma unroll
            for (int cc = 0; cc < C_; ++cc) w2c[cc] = w2s[nl][cc];
            #pragma unroll
            for (int ri = 0; ri < 2; ++ri)
                #pragma unroll
                for (int i = 0; i < 4; ++i) {
                    float h = acc[ri][rj][i][j] + bj;
                    h = h > 0.f ? h : 0.f;
                    #pragma unroll
                    for (int cc = 0; cc < C_; ++cc)
                        ps[ri][i][cc] = fmaf(h, w2c[cc], ps[ri][i][cc]);
                }
        }

    #pragma unroll
    for (int off = 1; off < 16; off <<= 1)
        #pragma unroll
        for (int ri = 0; ri < 2; ++ri)
            #pragma unroll
            for (int i = 0; i < 4; ++i)
                #pragma unroll
                for (int cc = 0; cc < C_; ++cc)
                    ps[ri][i][cc] += __shfl_xor(ps[ri][i][cc], off, 64);

    if (tx == 0)
        #pragma unroll
        for (int ri = 0; ri < 2; ++ri)
            #pragma unroll
            for (int i = 0; i < 4; ++i) {
                const int m = m0 + ri * 64 + (ty << 2) + i;
                #pragma unroll
                for (int cc = 0; cc < C_; ++cc)
                    atomicAdd(&pot[m * C_ + cc], ps[ri][i][cc]);
            }
}

// =========================================================================
// Kernel 3: Viterbi via max-plus associative scan (R4-R7, verified).
// =========================================================================
__global__ __launch_bounds__(64) void viterbi_kernel(
    const float* __restrict__ pot, const float* __restrict__ trans,
    const int* __restrict__ mask, float* __restrict__ decoded,
    float* __restrict__ seqlen, float* __restrict__ chain_out)
{
    const int b = blockIdx.x;
    const int lane = threadIdx.x;

    __shared__ float pl[S_ * C_];
    __shared__ unsigned int bpk[S_];
    __shared__ unsigned int gseg[64];
    __shared__ int bt[64];
    __shared__ int dec_s[S_];
    __shared__ int s_last;

    const float* pb = pot + b * (S_ * C_);
    for (int i = lane; i < S_ * C_; i += 64) pl[i] = pb[i];

    int mcnt = 0;
    const int* mb = mask + b * S_;
    for (int i = lane; i < S_; i += 64) mcnt += (mb[i] != 0) ? 1 : 0;
    #pragma unroll
    for (int off = 32; off >= 1; off >>= 1) mcnt += __shfl_xor(mcnt, off, 64);

    if (b == 0 && lane < C_ * C_) chain_out[lane] = trans[lane];

    float tr[C_][C_];
    #pragma unroll
    for (int p = 0; p < C_; ++p)
        #pragma unroll
        for (int c = 0; c < C_; ++c) tr[p][c] = trans[p * C_ + c];

    __syncthreads();

    const float NEG = -1.0e30f;

    float G[C_][C_];
    #pragma unroll
    for (int c = 0; c < C_; ++c)
        #pragma unroll
        for (int p = 0; p < C_; ++p) G[c][p] = (c == p) ? 0.f : NEG;

    for (int j = 1; j <= 8; ++j) {
        const int t = 8 * lane + j;
        if (t < S_) {
            float ng[C_][C_];
            #pragma unroll
            for (int c = 0; c < C_; ++c) {
                const float pc = pl[t * C_ + c];
                #pragma unroll
                for (int p = 0; p < C_; ++p) {
                    float m = tr[0][c] + G[0][p];
                    #pragma unroll
                    for (int q = 1; q < C_; ++q)
                        m = fmaxf(m, tr[q][c] + G[q][p]);
                    ng[c][p] = m + pc;
                }
            }
            #pragma unroll
            for (int c = 0; c < C_; ++c)
                #pragma unroll
                for (int p = 0; p < C_; ++p) G[c][p] = ng[c][p];
        }
    }

    #pragma unroll
    for (int d = 1; d < 64; d <<= 1) {
        float Q[C_][C_];
        #pragma unroll
        for (int q = 0; q < C_; ++q)
            #pragma unroll
            for (int p = 0; p < C_; ++p) Q[q][p] = __shfl_up(G[q][p], d, 64);
        if (lane >= d) {
            float ng[C_][C_];
            #pragma unroll
            for (int c = 0; c < C_; ++c)
                #pragma unroll
                for (int p = 0; p < C_; ++p) {
                    float m = G[c][0] + Q[0][p];
                    #pragma unroll
                    for (int q = 1; q < C_; ++q)
                        m = fmaxf(m, G[c][q] + Q[q][p]);
                    ng[c][p] = m;
                }
            #pragma unroll
            for (int c = 0; c < C_; ++c)
                #pragma unroll
                for (int p = 0; p < C_; ++p) G[c][p] = ng[c][p];
        }
    }

    float a[C_];
    {
        float E[C_][C_];
        #pragma unroll
        for (int c = 0; c < C_; ++c)
            #pragma unroll
            for (int p = 0; p < C_; ++p) E[c][p] = __shfl_up(G[c][p], 1, 64);
        float a0[C_];
        #pragma unroll
        for (int c = 0; c < C_; ++c) a0[c] = pl[c];
        if (lane == 0) {
            #pragma unroll
            for (int c = 0; c < C_; ++c) a[c] = a0[c];
        } else {
            #pragma unroll
            for (int c = 0; c < C_; ++c) {
                float m = E[c][0] + a0[0];
                #pragma unroll
                for (int q = 1; q < C_; ++q) m = fmaxf(m, E[c][q] + a0[q]);
                a[c] = m;
            }
        }
    }

    for (int j = 1; j <= 8; ++j) {
        const int t = 8 * lane + j;
        if (t < S_) {
            unsigned int mpack = 0;
            float na[C_];
            #pragma unroll
            for (int c = 0; c < C_; ++c) {
                float best = a[0] + tr[0][c];
                int arg = 0;
                #pragma unroll
                for (int p = 1; p < C_; ++p) {
                    const float s = a[p] + tr[p][c];
                    if (s > best) { best = s; arg = p; }
                }
                mpack |= (unsigned int)arg << (3 * c);
                na[c] = best + pl[t * C_ + c];
            }
            bpk[t] = mpack;
            #pragma unroll
            for (int c = 0; c < C_; ++c) a[c] = na[c];
        }
    }

    if (lane == 63) {
        float best = a[0];
        int arg = 0;
        #pragma unroll
        for (int p = 1; p < C_; ++p)
            if (a[p] > best) { best = a[p]; arg = p; }
        s_last = arg;
    }
    if (lane == 0) bpk[0] = 0;
    __syncthreads();

    const int last = s_last;

    unsigned int g = 0u | (1u << 3) | (2u << 6) | (3u << 9) | (4u << 12);
    #pragma unroll
    for (int j = 7; j >= 0; --j) {
        const int t = 8 * lane + j;
        if (t >= 1) {
            const unsigned int m = bpk[t];
            unsigned int ng = 0;
            #pragma unroll
            for (int x = 0; x < C_; ++x) {
                const unsigned int gx = (g >> (3 * x)) & 7u;
                ng |= ((m >> (3 * gx)) & 7u) << (3 * x);
            }
            g = ng;
        }
    }
    gseg[lane] = g;
    __syncthreads();

    if (lane == 0) {
        int cur = last;
        for (int l = 63; l >= 0; --l) {
            bt[l] = cur;
            cur = (int)((gseg[l] >> (3 * cur)) & 7u);
        }
        seqlen[b] = (float)mcnt;
    }
    __syncthreads();

    {
        int tag = bt[lane];
        const int t0 = 8 * lane;
        dec_s[t0 + 7] = tag;
        #pragma unroll
        for (int t = t0 + 7; t >= t0 + 1; --t) {
            tag = (int)((bpk[t] >> (3 * tag)) & 7u);
            dec_s[t - 1] = tag;
        }
    }
    __syncthreads();

    float* db = decoded + b * S_;
    for (int i = lane; i < S_; i += 64) db[i] = (float)dec_s[i];
}

// =========================================================================
extern "C" void kernel_launch(void* const* d_in, const int* in_sizes, int n_in,
                              void* d_out, int out_size, void* d_ws, size_t ws_size,
                              hipStream_t stream) {
    const float* hs    = (const float*)d_in[0];
    const int*   mask  = (const int*)  d_in[1];
    const float* W1    = (const float*)d_in[2];
    const float* b1    = (const float*)d_in[3];
    const float* W2    = (const float*)d_in[4];
    const float* b2    = (const float*)d_in[5];
    const float* chain = (const float*)d_in[6];
    const float* lb    = (const float*)d_in[7];
    const float* rb    = (const float*)d_in[8];

    float* out      = (float*)d_out;
    float* decoded  = out;
    float* pot      = out + M_;
    float* seq      = out + M_ + M_ * C_;
    float* chainout = seq + B_;

    const size_t need_w1 = (size_t)W1T_ELEMS * sizeof(unsigned short);            // 1.18 MB
    const size_t need_all = need_w1 + (size_t)XBF_ELEMS * sizeof(unsigned short); // 51.5 MB

    if (ws_size >= need_all) {
        unsigned short* w1t = (unsigned short*)d_ws;
        unsigned short* xbf = w1t + W1T_ELEMS;
        prep_all_kernel<<<PX_BLOCKS + PW_BLOCKS + PI_BLOCKS, 256, 0, stream>>>(
            hs, W1, b2, lb, rb, xbf, w1t, pot);
        gemm_256_kernel<<<384, 512, 0, stream>>>(xbf, w1t, b1, W2, pot);
    } else if (ws_size >= need_w1) {
        unsigned short* w1t = (unsigned short*)d_ws;
        init_pot_kernel<<<PI_BLOCKS, 256, 0, stream>>>(b2, lb, rb, pot);
        dim3 pgrid(H_ / 32, D_ / 32);
        prep_w1_kernel<<<pgrid, 256, 0, stream>>>(W1, w1t);
        gemm_bf16_kernel<<<1536, 256, 0, stream>>>(hs, w1t, b1, W2, pot);
    } else {
        init_pot_kernel<<<PI_BLOCKS, 256, 0, stream>>>(b2, lb, rb, pot);
        dim3 grid(H_ / 128, M_ / 128);
        gemm_relu_pot_kernel<<<grid, 256, 0, stream>>>(hs, W1, b1, W2, pot);
    }

    viterbi_kernel<<<B_, 64, 0, stream>>>(pot, chain, mask, decoded, seq, chainout);
}

// Round 2
// 277.077 us; speedup vs baseline: 1.0011x; 1.0011x over previous
//
#include <hip/hip_runtime.h>

// Problem constants
#define B_  64
#define S_  512
#define D_  768
#define H_  768
#define C_  5
#define M_  (B_ * S_)        // 32768 rows

typedef float f32x4 __attribute__((ext_vector_type(4)));
typedef short short8 __attribute__((ext_vector_type(8)));   // bf16x8 MFMA operand

#define W1T_ELEMS (D_ * H_)      // 589824  (bf16: 1.18 MB)
#define XBF_ELEMS (M_ * D_)      // 25165824 (bf16: 50.33 MB)

// prep_all grid partition
#define PX_BLOCKS   (XBF_ELEMS / (256 * 8))          // 12288
#define PW_BLOCKS   ((D_ / 32) * (H_ / 32))          // 576
#define PI_BLOCKS   ((M_ * C_ + 255) / 256)          // 640

__device__ __forceinline__ unsigned short f2bf(float f) {
    unsigned int u = __float_as_uint(f);
    u += 0x7FFFu + ((u >> 16) & 1u);     // RNE
    return (unsigned short)(u >> 16);
}

// =========================================================================
// Kernel 1: fused prep — prep_x | prep_w1 | init_pot in one dispatch
// =========================================================================
__global__ __launch_bounds__(256) void prep_all_kernel(
    const float* __restrict__ X, const float* __restrict__ W1,
    const float* __restrict__ b2, const float* __restrict__ lb,
    const float* __restrict__ rb,
    unsigned short* __restrict__ xbf, unsigned short* __restrict__ w1t,
    float* __restrict__ pot)
{
    __shared__ float t[32][33];
    const int bid = blockIdx.x;
    const int tid = threadIdx.x;

    if (bid < PX_BLOCKS) {
        // ---- X fp32 -> bf16 ----
        const size_t i0 = ((size_t)bid * 256 + tid) * 8;
        const float4 a = *(const float4*)(X + i0);
        const float4 b = *(const float4*)(X + i0 + 4);
        union { unsigned short u[8]; uint4 v; } o;
        o.u[0] = f2bf(a.x); o.u[1] = f2bf(a.y); o.u[2] = f2bf(a.z); o.u[3] = f2bf(a.w);
        o.u[4] = f2bf(b.x); o.u[5] = f2bf(b.y); o.u[6] = f2bf(b.z); o.u[7] = f2bf(b.w);
        *(uint4*)(xbf + i0) = o.v;
    } else if (bid < PX_BLOCKS + PW_BLOCKS) {
        // ---- W1 [k][n] fp32 -> w1t [n][k] bf16 (LDS-tiled transpose) ----
        const int b2i = bid - PX_BLOCKS;
        const int bx = b2i % (H_ / 32);       // n tile
        const int by = b2i / (H_ / 32);       // k tile
        const int lx = tid & 31, ly = tid >> 5;
        #pragma unroll
        for (int j = 0; j < 4; ++j)
            t[ly + 8 * j][lx] = W1[(by * 32 + ly + 8 * j) * H_ + bx * 32 + lx];
        __syncthreads();
        #pragma unroll
        for (int j = 0; j < 4; ++j)
            w1t[(size_t)(bx * 32 + ly + 8 * j) * D_ + by * 32 + lx] = f2bf(t[lx][ly + 8 * j]);
    } else {
        // ---- pot = b2 + boundaries ----
        const int idx = (bid - PX_BLOCKS - PW_BLOCKS) * 256 + tid;
        if (idx < M_ * C_) {
            const int c = idx % C_;
            const int tt = (idx / C_) & (S_ - 1);
            float v = b2[c];
            if (tt == 0)      v += lb[c];
            if (tt == S_ - 1) v += rb[c];
            pot[idx] = v;
        }
    }
}

// standalone prep_w1 for the fallback branch only
__global__ __launch_bounds__(256) void prep_w1_kernel(
    const float* __restrict__ W1, unsigned short* __restrict__ w1t)
{
    __shared__ float t[32][33];
    const int bx = blockIdx.x, by = blockIdx.y;
    const int lx = threadIdx.x & 31, ly = threadIdx.x >> 5;
    #pragma unroll
    for (int j = 0; j < 4; ++j)
        t[ly + 8 * j][lx] = W1[(by * 32 + ly + 8 * j) * H_ + bx * 32 + lx];
    __syncthreads();
    #pragma unroll
    for (int j = 0; j < 4; ++j)
        w1t[(size_t)(bx * 32 + ly + 8 * j) * D_ + by * 32 + lx] = f2bf(t[lx][ly + 8 * j]);
}

__global__ __launch_bounds__(256) void init_pot_kernel(
    const float* __restrict__ b2, const float* __restrict__ lb,
    const float* __restrict__ rb, float* __restrict__ pot)
{
    const int idx = blockIdx.x * 256 + threadIdx.x;
    if (idx < M_ * C_) {
        const int c = idx % C_;
        const int t = (idx / C_) & (S_ - 1);
        float v = b2[c];
        if (t == 0)      v += lb[c];
        if (t == S_ - 1) v += rb[c];
        pot[idx] = v;
    }
}

// =========================================================================
// Kernel 2: 128x128 tile, BK=64, SINGLE-buffered LDS (32 KB) bf16 MFMA GEMM.
//
// R0/R1 post-mortem: dbuf@64KB (2 blk/CU) and 8-phase@128KB (1 blk/CU) both
// plateau at ~95 µs with all pipes <16% busy — latency-bound at 8 waves/CU.
// Intra-block pipelining is neutral at this shape (proven twice); the untried
// axis is TLP. Single-buffering halves LDS to 32 KB -> 4 blocks/CU
// (VGPR ~96 -> 4 waves/SIMD quantum), 16 waves/CU. Blocks free-run against
// each other: one block's vmcnt(0)-drain stall is covered by the other
// three's MFMA/stage phases (m114 wave-level overlap). 2 barriers per K-tile:
//   bar (protect overwrite of prev tile's reads) -> stage 8x gload_lds ->
//   bar (implicit vmcnt(0)+lgkmcnt(0) drain) -> 16 ds_read_b128 -> 32 MFMA.
// =========================================================================
__device__ __forceinline__ void gload16(const void* g, void* l) {
    __builtin_amdgcn_global_load_lds(
        (const __attribute__((address_space(1))) unsigned int*)g,
        (__attribute__((address_space(3))) unsigned int*)l, 16, 0, 0);
}

__global__ __launch_bounds__(256, 4) void gemm_sb_kernel(
    const unsigned short* __restrict__ xbf,   // [M_, D_] bf16
    const unsigned short* __restrict__ w1t,   // [H_, D_] bf16 (n-major)
    const float* __restrict__ b1,
    const float* __restrict__ W2,             // [H_, C_]
    float* __restrict__ pot)                  // [M_, C_] pre-initialized
{
    // 128 rows x 64 cols bf16 = 8192 shorts per matrix (two 4096-el chunks)
    __shared__ __align__(16) unsigned short Asm[8192];   // 16 KB
    __shared__ __align__(16) unsigned short Bsm[8192];   // 16 KB (total 32 KB)

    const int tid  = threadIdx.x;
    const int lane = tid & 63, w = tid >> 6;
    const int wm   = w >> 1, wn = w & 1;
    const int i15  = lane & 15, quad = lane >> 4;

    // XCD swizzle: 6 n-blocks of an m-tile land on the same XCD (bid%8),
    // n-fastest so A-tile is shared in L2 across the 6 sibling blocks.
    const int bid = blockIdx.x;
    const int r8 = bid & 7, q8 = bid >> 3;
    const int nb = q8 % 6, mhi = q8 / 6;
    const int m0 = (mhi * 8 + r8) * 128;
    const int n0 = nb * 128;

    // staging: wave w owns row-groups {2w, 2w+1}; 2 chunks each => 4 A + 4 B
    const unsigned short* gA[2];
    const unsigned short* gB[2];
    int lofs[2];
    #pragma unroll
    for (int i = 0; i < 2; ++i) {
        const int g = 2 * w + i;
        gA[i] = xbf + (size_t)(m0 + g * 16 + i15) * D_ + quad * 8;
        gB[i] = w1t + (size_t)(n0 + g * 16 + i15) * D_ + quad * 8;
        lofs[i] = g * 512;
    }

    f32x4 acc[4][4];
    #pragma unroll
    for (int mi = 0; mi < 4; ++mi)
        #pragma unroll
        for (int ni = 0; ni < 4; ++ni)
            acc[mi][ni] = (f32x4){0.f, 0.f, 0.f, 0.f};

    #define KITERS (D_ / 64)    // 12
    for (int kt = 0; kt < KITERS; ++kt) {
        __syncthreads();   // prev tile's ds_reads complete before overwrite
        #pragma unroll
        for (int i = 0; i < 2; ++i) {
            gload16(gA[i],      &Asm[lofs[i]]);
            gload16(gA[i] + 32, &Asm[4096 + lofs[i]]);
            gload16(gB[i],      &Bsm[lofs[i]]);
            gload16(gB[i] + 32, &Bsm[4096 + lofs[i]]);
            gA[i] += 64; gB[i] += 64;
        }
        __syncthreads();   // vmcnt(0) drain: staged tile visible to all waves

        #pragma unroll
        for (int c = 0; c < 2; ++c) {
            const int cb = c * 4096;
            short8 af[4], bfr[4];
            #pragma unroll
            for (int mi = 0; mi < 4; ++mi)
                af[mi] = *(const short8*)&Asm[cb + (wm * 4 + mi) * 512 + quad * 128 + i15 * 8];
            #pragma unroll
            for (int ni = 0; ni < 4; ++ni)
                bfr[ni] = *(const short8*)&Bsm[cb + (wn * 4 + ni) * 512 + quad * 128 + i15 * 8];
            #pragma unroll
            for (int ni = 0; ni < 4; ++ni)
                #pragma unroll
                for (int mi = 0; mi < 4; ++mi)
                    acc[mi][ni] = __builtin_amdgcn_mfma_f32_16x16x32_bf16(
                        af[mi], bfr[ni], acc[mi][ni], 0, 0, 0);
        }
    }
    __syncthreads();   // all LDS reads done before epilogue aliases Asm

    // ---- epilogue: relu(h+b1)@W2, wave-partial -> LDS -> block atomics ----
    float* pp = (float*)&Asm[0];             // [2][128][C_] = 5120 B, fits

    float b1v[4], w2v[4][C_];
    #pragma unroll
    for (int ni = 0; ni < 4; ++ni) {
        const int col = n0 + wn * 64 + ni * 16 + i15;
        b1v[ni] = b1[col];
        #pragma unroll
        for (int cc = 0; cc < C_; ++cc) w2v[ni][cc] = W2[col * C_ + cc];
    }

    #pragma unroll
    for (int mi = 0; mi < 4; ++mi) {
        float ps[4][C_];
        #pragma unroll
        for (int r = 0; r < 4; ++r)
            #pragma unroll
            for (int cc = 0; cc < C_; ++cc) ps[r][cc] = 0.f;

        #pragma unroll
        for (int ni = 0; ni < 4; ++ni)
            #pragma unroll
            for (int r = 0; r < 4; ++r) {
                float h = acc[mi][ni][r] + b1v[ni];
                h = h > 0.f ? h : 0.f;
                #pragma unroll
                for (int cc = 0; cc < C_; ++cc)
                    ps[r][cc] = fmaf(h, w2v[ni][cc], ps[r][cc]);
            }

        #pragma unroll
        for (int off = 1; off < 16; off <<= 1)
            #pragma unroll
            for (int r = 0; r < 4; ++r)
                #pragma unroll
                for (int cc = 0; cc < C_; ++cc)
                    ps[r][cc] += __shfl_xor(ps[r][cc], off, 64);

        if (i15 == 0) {
            #pragma unroll
            for (int r = 0; r < 4; ++r) {
                const int row = wm * 64 + mi * 16 + quad * 4 + r;
                #pragma unroll
                for (int cc = 0; cc < C_; ++cc)
                    pp[(wn * 128 + row) * C_ + cc] = ps[r][cc];
            }
        }
    }
    __syncthreads();

    for (int idx = tid; idx < 128 * C_; idx += 256) {
        const int row = idx / C_, cc = idx % C_;
        atomicAdd(&pot[(size_t)(m0 + row) * C_ + cc],
                  pp[row * C_ + cc] + pp[(128 + row) * C_ + cc]);
    }
}

// =========================================================================
// Mid fallback (R3 kernel, proven): bf16 B from ws, fp32 A via LDS
// =========================================================================
__global__ __launch_bounds__(256) void gemm_bf16_kernel(
    const float* __restrict__ X,
    const unsigned short* __restrict__ w1t,
    const float* __restrict__ b1,
    const float* __restrict__ W2,
    float* __restrict__ pot)
{
    __shared__ __align__(16) float          Asm[128 * 32];
    __shared__ __align__(16) unsigned short Bsm[128 * 32];
    __shared__ float pp[2][128][C_];

    const int tid  = threadIdx.x;
    const int lane = tid & 63, w = tid >> 6;
    const int wm   = w >> 1, wn = w & 1;
    const int i15  = lane & 15, quad = lane >> 4;

    const int bid = blockIdx.x;
    const int r8 = bid & 7, q8 = bid >> 3;
    const int nb = q8 % 6, mhi = q8 / 6;
    const int m0 = (mhi * 8 + r8) * 128;
    const int n0 = nb * 128;

    const float* gA[4];
    float* lA[4];
    const unsigned short* gB[2];
    unsigned short* lB[2];
    #pragma unroll
    for (int i = 0; i < 4; ++i) {
        const int a = 4 * w + i, g = a >> 1, h = a & 1;
        gA[i] = X + (size_t)(m0 + g * 16 + i15) * D_ + (4 * h + quad) * 4;
        lA[i] = &Asm[g * 512 + h * 256];
    }
    #pragma unroll
    for (int i = 0; i < 2; ++i) {
        const int b = 2 * w + i;
        gB[i] = w1t + (size_t)(n0 + b * 16 + i15) * D_ + quad * 8;
        lB[i] = &Bsm[b * 512];
    }

    f32x4 acc[4][4];
    #pragma unroll
    for (int mi = 0; mi < 4; ++mi)
        #pragma unroll
        for (int ni = 0; ni < 4; ++ni)
            acc[mi][ni] = (f32x4){0.f, 0.f, 0.f, 0.f};

    for (int kt = 0; kt < D_ / 32; ++kt) {
        __syncthreads();
        #pragma unroll
        for (int i = 0; i < 4; ++i) { gload16(gA[i], lA[i]); gA[i] += 32; }
        #pragma unroll
        for (int i = 0; i < 2; ++i) { gload16(gB[i], lB[i]); gB[i] += 32; }
        __syncthreads();

        short8 af[4];
        #pragma unroll
        for (int mi = 0; mi < 4; ++mi) {
            const int row = wm * 64 + mi * 16 + i15;
            const int base = (row >> 4) * 512 + (row & 15) * 4 + quad * 128;
            const f32x4 lo = *(const f32x4*)&Asm[base];
            const f32x4 hi = *(const f32x4*)&Asm[base + 64];
            float f[8];
            *(f32x4*)&f[0] = lo; *(f32x4*)&f[4] = hi;
            union { short8 s; unsigned short u[8]; } cv;
            #pragma unroll
            for (int j = 0; j < 8; ++j) cv.u[j] = f2bf(f[j]);
            af[mi] = cv.s;
        }
        short8 bfr[4];
        #pragma unroll
        for (int ni = 0; ni < 4; ++ni) {
            const int row = wn * 64 + ni * 16 + i15;
            bfr[ni] = *(const short8*)&Bsm[(row >> 4) * 512 + quad * 128 + (row & 15) * 8];
        }
        #pragma unroll
        for (int ni = 0; ni < 4; ++ni)
            #pragma unroll
            for (int mi = 0; mi < 4; ++mi)
                acc[mi][ni] = __builtin_amdgcn_mfma_f32_16x16x32_bf16(
                    af[mi], bfr[ni], acc[mi][ni], 0, 0, 0);
    }

    float b1v[4], w2v[4][C_];
    #pragma unroll
    for (int ni = 0; ni < 4; ++ni) {
        const int col = n0 + wn * 64 + ni * 16 + i15;
        b1v[ni] = b1[col];
        #pragma unroll
        for (int cc = 0; cc < C_; ++cc) w2v[ni][cc] = W2[col * C_ + cc];
    }

    #pragma unroll
    for (int mi = 0; mi < 4; ++mi) {
        float ps[4][C_];
        #pragma unroll
        for (int r = 0; r < 4; ++r)
            #pragma unroll
            for (int cc = 0; cc < C_; ++cc) ps[r][cc] = 0.f;

        #pragma unroll
        for (int ni = 0; ni < 4; ++ni)
            #pragma unroll
            for (int r = 0; r < 4; ++r) {
                float h = acc[mi][ni][r] + b1v[ni];
                h = h > 0.f ? h : 0.f;
                #pragma unroll
                for (int cc = 0; cc < C_; ++cc)
                    ps[r][cc] = fmaf(h, w2v[ni][cc], ps[r][cc]);
            }

        #pragma unroll
        for (int off = 1; off < 16; off <<= 1)
            #pragma unroll
            for (int r = 0; r < 4; ++r)
                #pragma unroll
                for (int cc = 0; cc < C_; ++cc)
                    ps[r][cc] += __shfl_xor(ps[r][cc], off, 64);

        if (i15 == 0) {
            #pragma unroll
            for (int r = 0; r < 4; ++r) {
                const int row = wm * 64 + mi * 16 + quad * 4 + r;
                #pragma unroll
                for (int cc = 0; cc < C_; ++cc)
                    pp[wn][row][cc] = ps[r][cc];
            }
        }
    }
    __syncthreads();

    for (int idx = tid; idx < 128 * C_; idx += 256) {
        const int row = idx / C_, cc = idx % C_;
        atomicAdd(&pot[(size_t)(m0 + row) * C_ + cc],
                  pp[0][row][cc] + pp[1][row][cc]);
    }
}

// =========================================================================
// Last-resort fp32 GEMM (R1 kernel, proven) if ws < 1.18 MB
// =========================================================================
#define FBK 8
#define FLDS 132
__global__ __launch_bounds__(256) void gemm_relu_pot_kernel(
    const float* __restrict__ X, const float* __restrict__ W1,
    const float* __restrict__ b1, const float* __restrict__ W2,
    float* __restrict__ pot)
{
    __shared__ float As[FBK * FLDS];
    __shared__ float Bs[FBK * FLDS];
    __shared__ float w2s[128][C_];

    const int tid = threadIdx.x;
    const int tx = tid & 15, ty = tid >> 4;
    const int m0 = blockIdx.y * 128, n0 = blockIdx.x * 128;

    for (int idx = tid; idx < 128 * C_; idx += 256)
        w2s[idx / C_][idx % C_] = W2[(n0 + idx / C_) * C_ + idx % C_];

    float acc[2][2][4][4];
    #pragma unroll
    for (int a = 0; a < 2; ++a)
        #pragma unroll
        for (int b = 0; b < 2; ++b)
            #pragma unroll
            for (int i = 0; i < 4; ++i)
                #pragma unroll
                for (int j = 0; j < 4; ++j) acc[a][b][i][j] = 0.f;

    const int arow = tid >> 1, aq = tid & 1;
    const int brow = tid >> 5, bq = tid & 31;
    const float* Aptr = X + (m0 + arow) * D_ + aq * 4;
    const float* Bptr = W1 + brow * H_ + n0 + bq * 4;

    for (int kt = 0; kt < D_; kt += FBK) {
        const float4 avv = *(const float4*)Aptr;
        const float4 bvv = *(const float4*)Bptr;
        __syncthreads();
        As[(aq * 4 + 0) * FLDS + arow] = avv.x;
        As[(aq * 4 + 1) * FLDS + arow] = avv.y;
        As[(aq * 4 + 2) * FLDS + arow] = avv.z;
        As[(aq * 4 + 3) * FLDS + arow] = avv.w;
        *(float4*)&Bs[brow * FLDS + bq * 4] = bvv;
        __syncthreads();
        #pragma unroll
        for (int k = 0; k < FBK; ++k) {
            const float4 a0 = *(const float4*)&As[k * FLDS + (ty << 2)];
            const float4 a1 = *(const float4*)&As[k * FLDS + 64 + (ty << 2)];
            const float4 b0 = *(const float4*)&Bs[k * FLDS + (tx << 2)];
            const float4 b1r = *(const float4*)&Bs[k * FLDS + 64 + (tx << 2)];
            const float ar[2][4] = {{a0.x,a0.y,a0.z,a0.w},{a1.x,a1.y,a1.z,a1.w}};
            const float br[2][4] = {{b0.x,b0.y,b0.z,b0.w},{b1r.x,b1r.y,b1r.z,b1r.w}};
            #pragma unroll
            for (int ri = 0; ri < 2; ++ri)
                #pragma unroll
                for (int i = 0; i < 4; ++i)
                    #pragma unroll
                    for (int rj = 0; rj < 2; ++rj)
                        #pragma unroll
                        for (int j = 0; j < 4; ++j)
                            acc[ri][rj][i][j] = fmaf(ar[ri][i], br[rj][j], acc[ri][rj][i][j]);
        }
        Aptr += FBK;
        Bptr += FBK * H_;
    }

    float ps[2][4][C_];
    #pragma unroll
    for (int ri = 0; ri < 2; ++ri)
        #pragma unroll
        for (int i = 0; i < 4; ++i)
            #pragma unroll
            for (int cc = 0; cc < C_; ++cc) ps[ri][i][cc] = 0.f;

    #pragma unroll
    for (int rj = 0; rj < 2; ++rj)
        #pragma unroll
        for (int j = 0; j < 4; ++j) {
            const int nl = rj * 64 + (tx << 2) + j;
            const float bj = b1[n0 + nl];
            float w2c[C_];
            #pragma unroll
            for (int cc = 0; cc < C_; ++cc) w2c[cc] = w2s[nl][cc];
            #pragma unroll
            for (int ri = 0; ri < 2; ++ri)
                #pragma unroll
                for (int i = 0; i < 4; ++i) {
                    float h = acc[ri][rj][i][j] + bj;
                    h = h > 0.f ? h : 0.f;
                    #pragma unroll
                    for (int cc = 0; cc < C_; ++cc)
                        ps[ri][i][cc] = fmaf(h, w2c[cc], ps[ri][i][cc]);
                }
        }

    #pragma unroll
    for (int off = 1; off < 16; off <<= 1)
        #pragma unroll
        for (int ri = 0; ri < 2; ++ri)
            #pragma unroll
            for (int i = 0; i < 4; ++i)
                #pragma unroll
                for (int cc = 0; cc < C_; ++cc)
                    ps[ri][i][cc] += __shfl_xor(ps[ri][i][cc], off, 64);

    if (tx == 0)
        #pragma unroll
        for (int ri = 0; ri < 2; ++ri)
            #pragma unroll
            for (int i = 0; i < 4; ++i) {
                const int m = m0 + ri * 64 + (ty << 2) + i;
                #pragma unroll
                for (int cc = 0; cc < C_; ++cc)
                    atomicAdd(&pot[m * C_ + cc], ps[ri][i][cc]);
            }
}

// =========================================================================
// Kernel 3: Viterbi via max-plus associative scan (R4-R7, verified).
// =========================================================================
__global__ __launch_bounds__(64) void viterbi_kernel(
    const float* __restrict__ pot, const float* __restrict__ trans,
    const int* __restrict__ mask, float* __restrict__ decoded,
    float* __restrict__ seqlen, float* __restrict__ chain_out)
{
    const int b = blockIdx.x;
    const int lane = threadIdx.x;

    __shared__ float pl[S_ * C_];
    __shared__ unsigned int bpk[S_];
    __shared__ unsigned int gseg[64];
    __shared__ int bt[64];
    __shared__ int dec_s[S_];
    __shared__ int s_last;

    const float* pb = pot + b * (S_ * C_);
    for (int i = lane; i < S_ * C_; i += 64) pl[i] = pb[i];

    int mcnt = 0;
    const int* mb = mask + b * S_;
    for (int i = lane; i < S_; i += 64) mcnt += (mb[i] != 0) ? 1 : 0;
    #pragma unroll
    for (int off = 32; off >= 1; off >>= 1) mcnt += __shfl_xor(mcnt, off, 64);

    if (b == 0 && lane < C_ * C_) chain_out[lane] = trans[lane];

    float tr[C_][C_];
    #pragma unroll
    for (int p = 0; p < C_; ++p)
        #pragma unroll
        for (int c = 0; c < C_; ++c) tr[p][c] = trans[p * C_ + c];

    __syncthreads();

    const float NEG = -1.0e30f;

    float G[C_][C_];
    #pragma unroll
    for (int c = 0; c < C_; ++c)
        #pragma unroll
        for (int p = 0; p < C_; ++p) G[c][p] = (c == p) ? 0.f : NEG;

    for (int j = 1; j <= 8; ++j) {
        const int t = 8 * lane + j;
        if (t < S_) {
            float ng[C_][C_];
            #pragma unroll
            for (int c = 0; c < C_; ++c) {
                const float pc = pl[t * C_ + c];
                #pragma unroll
                for (int p = 0; p < C_; ++p) {
                    float m = tr[0][c] + G[0][p];
                    #pragma unroll
                    for (int q = 1; q < C_; ++q)
                        m = fmaxf(m, tr[q][c] + G[q][p]);
                    ng[c][p] = m + pc;
                }
            }
            #pragma unroll
            for (int c = 0; c < C_; ++c)
                #pragma unroll
                for (int p = 0; p < C_; ++p) G[c][p] = ng[c][p];
        }
    }

    #pragma unroll
    for (int d = 1; d < 64; d <<= 1) {
        float Q[C_][C_];
        #pragma unroll
        for (int q = 0; q < C_; ++q)
            #pragma unroll
            for (int p = 0; p < C_; ++p) Q[q][p] = __shfl_up(G[q][p], d, 64);
        if (lane >= d) {
            float ng[C_][C_];
            #pragma unroll
            for (int c = 0; c < C_; ++c)
                #pragma unroll
                for (int p = 0; p < C_; ++p) {
                    float m = G[c][0] + Q[0][p];
                    #pragma unroll
                    for (int q = 1; q < C_; ++q)
                        m = fmaxf(m, G[c][q] + Q[q][p]);
                    ng[c][p] = m;
                }
            #pragma unroll
            for (int c = 0; c < C_; ++c)
                #pragma unroll
                for (int p = 0; p < C_; ++p) G[c][p] = ng[c][p];
        }
    }

    float a[C_];
    {
        float E[C_][C_];
        #pragma unroll
        for (int c = 0; c < C_; ++c)
            #pragma unroll
            for (int p = 0; p < C_; ++p) E[c][p] = __shfl_up(G[c][p], 1, 64);
        float a0[C_];
        #pragma unroll
        for (int c = 0; c < C_; ++c) a0[c] = pl[c];
        if (lane == 0) {
            #pragma unroll
            for (int c = 0; c < C_; ++c) a[c] = a0[c];
        } else {
            #pragma unroll
            for (int c = 0; c < C_; ++c) {
                float m = E[c][0] + a0[0];
                #pragma unroll
                for (int q = 1; q < C_; ++q) m = fmaxf(m, E[c][q] + a0[q]);
                a[c] = m;
            }
        }
    }

    for (int j = 1; j <= 8; ++j) {
        const int t = 8 * lane + j;
        if (t < S_) {
            unsigned int mpack = 0;
            float na[C_];
            #pragma unroll
            for (int c = 0; c < C_; ++c) {
                float best = a[0] + tr[0][c];
                int arg = 0;
                #pragma unroll
                for (int p = 1; p < C_; ++p) {
                    const float s = a[p] + tr[p][c];
                    if (s > best) { best = s; arg = p; }
                }
                mpack |= (unsigned int)arg << (3 * c);
                na[c] = best + pl[t * C_ + c];
            }
            bpk[t] = mpack;
            #pragma unroll
            for (int c = 0; c < C_; ++c) a[c] = na[c];
        }
    }

    if (lane == 63) {
        float best = a[0];
        int arg = 0;
        #pragma unroll
        for (int p = 1; p < C_; ++p)
            if (a[p] > best) { best = a[p]; arg = p; }
        s_last = arg;
    }
    if (lane == 0) bpk[0] = 0;
    __syncthreads();

    const int last = s_last;

    unsigned int g = 0u | (1u << 3) | (2u << 6) | (3u << 9) | (4u << 12);
    #pragma unroll
    for (int j = 7; j >= 0; --j) {
        const int t = 8 * lane + j;
        if (t >= 1) {
            const unsigned int m = bpk[t];
            unsigned int ng = 0;
            #pragma unroll
            for (int x = 0; x < C_; ++x) {
                const unsigned int gx = (g >> (3 * x)) & 7u;
                ng |= ((m >> (3 * gx)) & 7u) << (3 * x);
            }
            g = ng;
        }
    }
    gseg[lane] = g;
    __syncthreads();

    if (lane == 0) {
        int cur = last;
        for (int l = 63; l >= 0; --l) {
            bt[l] = cur;
            cur = (int)((gseg[l] >> (3 * cur)) & 7u);
        }
        seqlen[b] = (float)mcnt;
    }
    __syncthreads();

    {
        int tag = bt[lane];
        const int t0 = 8 * lane;
        dec_s[t0 + 7] = tag;
        #pragma unroll
        for (int t = t0 + 7; t >= t0 + 1; --t) {
            tag = (int)((bpk[t] >> (3 * tag)) & 7u);
            dec_s[t - 1] = tag;
        }
    }
    __syncthreads();

    float* db = decoded + b * S_;
    for (int i = lane; i < S_; i += 64) db[i] = (float)dec_s[i];
}

// =========================================================================
extern "C" void kernel_launch(void* const* d_in, const int* in_sizes, int n_in,
                              void* d_out, int out_size, void* d_ws, size_t ws_size,
                              hipStream_t stream) {
    const float* hs    = (const float*)d_in[0];
    const int*   mask  = (const int*)  d_in[1];
    const float* W1    = (const float*)d_in[2];
    const float* b1    = (const float*)d_in[3];
    const float* W2    = (const float*)d_in[4];
    const float* b2    = (const float*)d_in[5];
    const float* chain = (const float*)d_in[6];
    const float* lb    = (const float*)d_in[7];
    const float* rb    = (const float*)d_in[8];

    float* out      = (float*)d_out;
    float* decoded  = out;
    float* pot      = out + M_;
    float* seq      = out + M_ + M_ * C_;
    float* chainout = seq + B_;

    const size_t need_w1 = (size_t)W1T_ELEMS * sizeof(unsigned short);            // 1.18 MB
    const size_t need_all = need_w1 + (size_t)XBF_ELEMS * sizeof(unsigned short); // 51.5 MB

    if (ws_size >= need_all) {
        unsigned short* w1t = (unsigned short*)d_ws;
        unsigned short* xbf = w1t + W1T_ELEMS;
        prep_all_kernel<<<PX_BLOCKS + PW_BLOCKS + PI_BLOCKS, 256, 0, stream>>>(
            hs, W1, b2, lb, rb, xbf, w1t, pot);
        gemm_sb_kernel<<<1536, 256, 0, stream>>>(xbf, w1t, b1, W2, pot);
    } else if (ws_size >= need_w1) {
        unsigned short* w1t = (unsigned short*)d_ws;
        init_pot_kernel<<<PI_BLOCKS, 256, 0, stream>>>(b2, lb, rb, pot);
        dim3 pgrid(H_ / 32, D_ / 32);
        prep_w1_kernel<<<pgrid, 256, 0, stream>>>(W1, w1t);
        gemm_bf16_kernel<<<1536, 256, 0, stream>>>(hs, w1t, b1, W2, pot);
    } else {
        init_pot_kernel<<<PI_BLOCKS, 256, 0, stream>>>(b2, lb, rb, pot);
        dim3 grid(H_ / 128, M_ / 128);
        gemm_relu_pot_kernel<<<grid, 256, 0, stream>>>(hs, W1, b1, W2, pot);
    }

    viterbi_kernel<<<B_, 64, 0, stream>>>(pot, chain, mask, decoded, seq, chainout);
}

// Round 3
// 271.446 us; speedup vs baseline: 1.0219x; 1.0207x over previous
//
#include <hip/hip_runtime.h>

// Problem constants
#define B_  64
#define S_  512
#define D_  768
#define H_  768
#define C_  5
#define M_  (B_ * S_)        // 32768 rows

typedef float f32x4 __attribute__((ext_vector_type(4)));
typedef short short8 __attribute__((ext_vector_type(8)));   // bf16x8 MFMA operand

#define W1T_ELEMS (D_ * H_)      // 589824  (bf16: 1.18 MB)

__device__ __forceinline__ unsigned short f2bf(float f) {
    unsigned int u = __float_as_uint(f);
    u += 0x7FFFu + ((u >> 16) & 1u);     // RNE
    return (unsigned short)(u >> 16);
}

__device__ __forceinline__ void gload16(const void* g, void* l) {
    __builtin_amdgcn_global_load_lds(
        (const __attribute__((address_space(1))) unsigned int*)g,
        (__attribute__((address_space(3))) unsigned int*)l, 16, 0, 0);
}

// =========================================================================
// prep: W1 [k][n] fp32 -> w1t [n][k] bf16 (LDS-tiled transpose). Tiny.
// =========================================================================
__global__ __launch_bounds__(256) void prep_w1_kernel(
    const float* __restrict__ W1, unsigned short* __restrict__ w1t)
{
    __shared__ float t[32][33];
    const int bx = blockIdx.x, by = blockIdx.y;
    const int lx = threadIdx.x & 31, ly = threadIdx.x >> 5;
    #pragma unroll
    for (int j = 0; j < 4; ++j)
        t[ly + 8 * j][lx] = W1[(by * 32 + ly + 8 * j) * H_ + bx * 32 + lx];
    __syncthreads();
    #pragma unroll
    for (int j = 0; j < 4; ++j)
        w1t[(size_t)(bx * 32 + ly + 8 * j) * D_ + by * 32 + lx] = f2bf(t[lx][ly + 8 * j]);
}

__global__ __launch_bounds__(256) void init_pot_kernel(
    const float* __restrict__ b2, const float* __restrict__ lb,
    const float* __restrict__ rb, float* __restrict__ pot)
{
    const int idx = blockIdx.x * 256 + threadIdx.x;
    if (idx < M_ * C_) {
        const int c = idx % C_;
        const int t = (idx / C_) & (S_ - 1);
        float v = b2[c];
        if (t == 0)      v += lb[c];
        if (t == S_ - 1) v += rb[c];
        pot[idx] = v;
    }
}

// =========================================================================
// Kernel 2 (R3 redesign): full-N blocks — 64 rows x N=768 per block.
//
// R0-R2 post-mortem: three schedules (dbuf/8-phase/single-buf, 8-16 waves/CU)
// all plateau at ~95-103 us with every pipe <16% busy. The invariant is the
// ~590 MB of A-tile re-fetches pushed through the L2-fill path (~19 B/cy/CU
// observed service rate). Fix the ALGORITHM: W1 (1.18 MB bf16) is L2-resident
// in every XCD, so block over M only; each block reads its X rows ONCE
// (fp32, converted in-register), streams all of W1 from hot L2 per K-step,
// owns the full n-reduction -> direct pot store, no atomics, no init_pot,
// no xbf materialization (prep-X pass deleted).
//
// 512 thr / 8 waves, wave tile 64x96 (1m x 8n), 12 K-steps of 64:
//   bar -> stage(12 B gload16 + A: 2 float4 -> f2bf -> 1 ds_write_b128)
//   bar(vmcnt0+lgkmcnt0 drain) -> 2x { 4 A-frag + 6 B-frag ds_read, 24 MFMA }
// LDS: A 4x2x512 shorts (8 KB) + B 48x2x512 shorts (96 KB) = 104 KB,
// single-buffered; epilogue pp[8][64][5] f32 aliases Blds.
// =========================================================================
__global__ __launch_bounds__(512, 2) void gemm_fulln_kernel(
    const float* __restrict__ X,              // [M_, D_] fp32
    const unsigned short* __restrict__ w1t,   // [H_, D_] bf16 (n-major)
    const float* __restrict__ b1,
    const float* __restrict__ W2,             // [H_, C_]
    const float* __restrict__ b2,
    const float* __restrict__ lb,
    const float* __restrict__ rb,
    float* __restrict__ pot)                  // [M_, C_] written directly
{
    __shared__ __align__(16) unsigned short Alds[4 * 2 * 512];    // 8 KB
    __shared__ __align__(16) unsigned short Blds[48 * 2 * 512];   // 96 KB

    const int tid  = threadIdx.x;
    const int lane = tid & 63, w = tid >> 6;       // wave 0..7
    const int i15  = lane & 15, quad = lane >> 4;
    const int m0   = blockIdx.x * 64;

    // ---- A staging map: thread t handles (row = t>>3, k octet (t&7)*8) ----
    const int arow = tid >> 3;              // 0..63
    const int ak0  = (tid & 7) * 8;         // 0..56
    const float* aSrc = X + (size_t)(m0 + arow) * D_ + ak0;
    unsigned short* aDst = &Alds[((arow >> 4) * 2 + (ak0 >> 5)) * 512
                                 + ((ak0 >> 3) & 3) * 128 + (arow & 15) * 8];

    // ---- B staging: wave w stages n-groups [6w, 6w+6) via gload16 ----
    const unsigned short* bSrc = w1t + (size_t)(6 * w * 16 + i15) * D_ + quad * 8;

    f32x4 acc[4][6];
    #pragma unroll
    for (int mi = 0; mi < 4; ++mi)
        #pragma unroll
        for (int ni = 0; ni < 6; ++ni)
            acc[mi][ni] = (f32x4){0.f, 0.f, 0.f, 0.f};

    #define STAGE(KB) do {                                                   \
        _Pragma("unroll")                                                    \
        for (int gi = 0; gi < 6; ++gi) {                                     \
            const unsigned short* s = bSrc + (size_t)gi * 16 * D_ + (KB);    \
            gload16(s,      &Blds[((6 * w + gi) * 2 + 0) * 512]);            \
            gload16(s + 32, &Blds[((6 * w + gi) * 2 + 1) * 512]);            \
        }                                                                    \
        {                                                                    \
            const float4 x0 = *(const float4*)(aSrc + (KB));                 \
            const float4 x1 = *(const float4*)(aSrc + (KB) + 4);             \
            union { unsigned short u[8]; uint4 v; } o;                       \
            o.u[0] = f2bf(x0.x); o.u[1] = f2bf(x0.y);                        \
            o.u[2] = f2bf(x0.z); o.u[3] = f2bf(x0.w);                        \
            o.u[4] = f2bf(x1.x); o.u[5] = f2bf(x1.y);                        \
            o.u[6] = f2bf(x1.z); o.u[7] = f2bf(x1.w);                        \
            *(uint4*)aDst = o.v;                                             \
        }                                                                    \
    } while (0)

    STAGE(0);
    #define KSTEPS (D_ / 64)     // 12
    for (int kt = 0; kt < KSTEPS; ++kt) {
        __syncthreads();   // staged tile visible (drains vmcnt+lgkmcnt)

        #pragma unroll
        for (int kh = 0; kh < 2; ++kh) {
            short8 af[4], bfr[6];
            #pragma unroll
            for (int mi = 0; mi < 4; ++mi)
                af[mi] = *(const short8*)&Alds[(mi * 2 + kh) * 512 + lane * 8];
            #pragma unroll
            for (int ni = 0; ni < 6; ++ni)
                bfr[ni] = *(const short8*)&Blds[((w * 6 + ni) * 2 + kh) * 512 + lane * 8];
            #pragma unroll
            for (int ni = 0; ni < 6; ++ni)
                #pragma unroll
                for (int mi = 0; mi < 4; ++mi)
                    acc[mi][ni] = __builtin_amdgcn_mfma_f32_16x16x32_bf16(
                        af[mi], bfr[ni], acc[mi][ni], 0, 0, 0);
        }

        if (kt + 1 < KSTEPS) {
            __syncthreads();   // all reads of this tile done before overwrite
            STAGE((kt + 1) * 64);
        }
    }
    __syncthreads();   // last reads done before pp aliases Blds

    // ---- epilogue: relu(h+b1)@W2, full-n owned by block -> direct store ----
    float* pp = (float*)&Blds[0];            // [8][64][C_] = 10240 B

    float b1v[6], w2v[6][C_];
    #pragma unroll
    for (int ni = 0; ni < 6; ++ni) {
        const int col = w * 96 + ni * 16 + i15;
        b1v[ni] = b1[col];
        #pragma unroll
        for (int cc = 0; cc < C_; ++cc) w2v[ni][cc] = W2[col * C_ + cc];
    }

    #pragma unroll
    for (int mi = 0; mi < 4; ++mi) {
        float ps[4][C_];
        #pragma unroll
        for (int r = 0; r < 4; ++r)
            #pragma unroll
            for (int cc = 0; cc < C_; ++cc) ps[r][cc] = 0.f;

        #pragma unroll
        for (int ni = 0; ni < 6; ++ni)
            #pragma unroll
            for (int r = 0; r < 4; ++r) {
                float h = acc[mi][ni][r] + b1v[ni];
                h = h > 0.f ? h : 0.f;
                #pragma unroll
                for (int cc = 0; cc < C_; ++cc)
                    ps[r][cc] = fmaf(h, w2v[ni][cc], ps[r][cc]);
            }

        // reduce over the 16 cols held across i15 lanes (quad = rows, keep)
        #pragma unroll
        for (int off = 1; off < 16; off <<= 1)
            #pragma unroll
            for (int r = 0; r < 4; ++r)
                #pragma unroll
                for (int cc = 0; cc < C_; ++cc)
                    ps[r][cc] += __shfl_xor(ps[r][cc], off, 64);

        if (i15 == 0) {
            #pragma unroll
            for (int r = 0; r < 4; ++r) {
                const int row = mi * 16 + quad * 4 + r;
                #pragma unroll
                for (int cc = 0; cc < C_; ++cc)
                    pp[(w * 64 + row) * C_ + cc] = ps[r][cc];
            }
        }
    }
    __syncthreads();

    for (int idx = tid; idx < 64 * C_; idx += 512) {
        const int row = idx / C_, cc = idx % C_;
        float s = b2[cc];
        #pragma unroll
        for (int wv = 0; wv < 8; ++wv)
            s += pp[(wv * 64 + row) * C_ + cc];
        const int gm = m0 + row;
        const int tt = gm & (S_ - 1);
        if (tt == 0)      s += lb[cc];
        if (tt == S_ - 1) s += rb[cc];
        pot[(size_t)gm * C_ + cc] = s;
    }
}

// =========================================================================
// Last-resort fp32 GEMM (R1 kernel, proven) if ws < 1.18 MB
// =========================================================================
#define FBK 8
#define FLDS 132
__global__ __launch_bounds__(256) void gemm_relu_pot_kernel(
    const float* __restrict__ X, const float* __restrict__ W1,
    const float* __restrict__ b1, const float* __restrict__ W2,
    float* __restrict__ pot)
{
    __shared__ float As[FBK * FLDS];
    __shared__ float Bs[FBK * FLDS];
    __shared__ float w2s[128][C_];

    const int tid = threadIdx.x;
    const int tx = tid & 15, ty = tid >> 4;
    const int m0 = blockIdx.y * 128, n0 = blockIdx.x * 128;

    for (int idx = tid; idx < 128 * C_; idx += 256)
        w2s[idx / C_][idx % C_] = W2[(n0 + idx / C_) * C_ + idx % C_];

    float acc[2][2][4][4];
    #pragma unroll
    for (int a = 0; a < 2; ++a)
        #pragma unroll
        for (int b = 0; b < 2; ++b)
            #pragma unroll
            for (int i = 0; i < 4; ++i)
                #pragma unroll
                for (int j = 0; j < 4; ++j) acc[a][b][i][j] = 0.f;

    const int arow = tid >> 1, aq = tid & 1;
    const int brow = tid >> 5, bq = tid & 31;
    const float* Aptr = X + (m0 + arow) * D_ + aq * 4;
    const float* Bptr = W1 + brow * H_ + n0 + bq * 4;

    for (int kt = 0; kt < D_; kt += FBK) {
        const float4 avv = *(const float4*)Aptr;
        const float4 bvv = *(const float4*)Bptr;
        __syncthreads();
        As[(aq * 4 + 0) * FLDS + arow] = avv.x;
        As[(aq * 4 + 1) * FLDS + arow] = avv.y;
        As[(aq * 4 + 2) * FLDS + arow] = avv.z;
        As[(aq * 4 + 3) * FLDS + arow] = avv.w;
        *(float4*)&Bs[brow * FLDS + bq * 4] = bvv;
        __syncthreads();
        #pragma unroll
        for (int k = 0; k < FBK; ++k) {
            const float4 a0 = *(const float4*)&As[k * FLDS + (ty << 2)];
            const float4 a1 = *(const float4*)&As[k * FLDS + 64 + (ty << 2)];
            const float4 b0 = *(const float4*)&Bs[k * FLDS + (tx << 2)];
            const float4 b1r = *(const float4*)&Bs[k * FLDS + 64 + (tx << 2)];
            const float ar[2][4] = {{a0.x,a0.y,a0.z,a0.w},{a1.x,a1.y,a1.z,a1.w}};
            const float br[2][4] = {{b0.x,b0.y,b0.z,b0.w},{b1r.x,b1r.y,b1r.z,b1r.w}};
            #pragma unroll
            for (int ri = 0; ri < 2; ++ri)
                #pragma unroll
                for (int i = 0; i < 4; ++i)
                    #pragma unroll
                    for (int rj = 0; rj < 2; ++rj)
                        #pragma unroll
                        for (int j = 0; j < 4; ++j)
                            acc[ri][rj][i][j] = fmaf(ar[ri][i], br[rj][j], acc[ri][rj][i][j]);
        }
        Aptr += FBK;
        Bptr += FBK * H_;
    }

    float ps[2][4][C_];
    #pragma unroll
    for (int ri = 0; ri < 2; ++ri)
        #pragma unroll
        for (int i = 0; i < 4; ++i)
            #pragma unroll
            for (int cc = 0; cc < C_; ++cc) ps[ri][i][cc] = 0.f;

    #pragma unroll
    for (int rj = 0; rj < 2; ++rj)
        #pragma unroll
        for (int j = 0; j < 4; ++j) {
            const int nl = rj * 64 + (tx << 2) + j;
            const float bj = b1[n0 + nl];
            float w2c[C_];
            #pragma unroll
            for (int cc = 0; cc < C_; ++cc) w2c[cc] = w2s[nl][cc];
            #pragma unroll
            for (int ri = 0; ri < 2; ++ri)
                #pragma unroll
                for (int i = 0; i < 4; ++i) {
                    float h = acc[ri][rj][i][j] + bj;
                    h = h > 0.f ? h : 0.f;
                    #pragma unroll
                    for (int cc = 0; cc < C_; ++cc)
                        ps[ri][i][cc] = fmaf(h, w2c[cc], ps[ri][i][cc]);
                }
        }

    #pragma unroll
    for (int off = 1; off < 16; off <<= 1)
        #pragma unroll
        for (int ri = 0; ri < 2; ++ri)
            #pragma unroll
            for (int i = 0; i < 4; ++i)
                #pragma unroll
                for (int cc = 0; cc < C_; ++cc)
                    ps[ri][i][cc] += __shfl_xor(ps[ri][i][cc], off, 64);

    if (tx == 0)
        #pragma unroll
        for (int ri = 0; ri < 2; ++ri)
            #pragma unroll
            for (int i = 0; i < 4; ++i) {
                const int m = m0 + ri * 64 + (ty << 2) + i;
                #pragma unroll
                for (int cc = 0; cc < C_; ++cc)
                    atomicAdd(&pot[m * C_ + cc], ps[ri][i][cc]);
            }
}

// =========================================================================
// Kernel 3: Viterbi via max-plus associative scan (verified).
// =========================================================================
__global__ __launch_bounds__(64) void viterbi_kernel(
    const float* __restrict__ pot, const float* __restrict__ trans,
    const int* __restrict__ mask, float* __restrict__ decoded,
    float* __restrict__ seqlen, float* __restrict__ chain_out)
{
    const int b = blockIdx.x;
    const int lane = threadIdx.x;

    __shared__ float pl[S_ * C_];
    __shared__ unsigned int bpk[S_];
    __shared__ unsigned int gseg[64];
    __shared__ int bt[64];
    __shared__ int dec_s[S_];
    __shared__ int s_last;

    const float* pb = pot + b * (S_ * C_);
    for (int i = lane; i < S_ * C_; i += 64) pl[i] = pb[i];

    int mcnt = 0;
    const int* mb = mask + b * S_;
    for (int i = lane; i < S_; i += 64) mcnt += (mb[i] != 0) ? 1 : 0;
    #pragma unroll
    for (int off = 32; off >= 1; off >>= 1) mcnt += __shfl_xor(mcnt, off, 64);

    if (b == 0 && lane < C_ * C_) chain_out[lane] = trans[lane];

    float tr[C_][C_];
    #pragma unroll
    for (int p = 0; p < C_; ++p)
        #pragma unroll
        for (int c = 0; c < C_; ++c) tr[p][c] = trans[p * C_ + c];

    __syncthreads();

    const float NEG = -1.0e30f;

    float G[C_][C_];
    #pragma unroll
    for (int c = 0; c < C_; ++c)
        #pragma unroll
        for (int p = 0; p < C_; ++p) G[c][p] = (c == p) ? 0.f : NEG;

    for (int j = 1; j <= 8; ++j) {
        const int t = 8 * lane + j;
        if (t < S_) {
            float ng[C_][C_];
            #pragma unroll
            for (int c = 0; c < C_; ++c) {
                const float pc = pl[t * C_ + c];
                #pragma unroll
                for (int p = 0; p < C_; ++p) {
                    float m = tr[0][c] + G[0][p];
                    #pragma unroll
                    for (int q = 1; q < C_; ++q)
                        m = fmaxf(m, tr[q][c] + G[q][p]);
                    ng[c][p] = m + pc;
                }
            }
            #pragma unroll
            for (int c = 0; c < C_; ++c)
                #pragma unroll
                for (int p = 0; p < C_; ++p) G[c][p] = ng[c][p];
        }
    }

    #pragma unroll
    for (int d = 1; d < 64; d <<= 1) {
        float Q[C_][C_];
        #pragma unroll
        for (int q = 0; q < C_; ++q)
            #pragma unroll
            for (int p = 0; p < C_; ++p) Q[q][p] = __shfl_up(G[q][p], d, 64);
        if (lane >= d) {
            float ng[C_][C_];
            #pragma unroll
            for (int c = 0; c < C_; ++c)
                #pragma unroll
                for (int p = 0; p < C_; ++p) {
                    float m = G[c][0] + Q[0][p];
                    #pragma unroll
                    for (int q = 1; q < C_; ++q)
                        m = fmaxf(m, G[c][q] + Q[q][p]);
                    ng[c][p] = m;
                }
            #pragma unroll
            for (int c = 0; c < C_; ++c)
                #pragma unroll
                for (int p = 0; p < C_; ++p) G[c][p] = ng[c][p];
        }
    }

    float a[C_];
    {
        float E[C_][C_];
        #pragma unroll
        for (int c = 0; c < C_; ++c)
            #pragma unroll
            for (int p = 0; p < C_; ++p) E[c][p] = __shfl_up(G[c][p], 1, 64);
        float a0[C_];
        #pragma unroll
        for (int c = 0; c < C_; ++c) a0[c] = pl[c];
        if (lane == 0) {
            #pragma unroll
            for (int c = 0; c < C_; ++c) a[c] = a0[c];
        } else {
            #pragma unroll
            for (int c = 0; c < C_; ++c) {
                float m = E[c][0] + a0[0];
                #pragma unroll
                for (int q = 1; q < C_; ++q) m = fmaxf(m, E[c][q] + a0[q]);
                a[c] = m;
            }
        }
    }

    for (int j = 1; j <= 8; ++j) {
        const int t = 8 * lane + j;
        if (t < S_) {
            unsigned int mpack = 0;
            float na[C_];
            #pragma unroll
            for (int c = 0; c < C_; ++c) {
                float best = a[0] + tr[0][c];
                int arg = 0;
                #pragma unroll
                for (int p = 1; p < C_; ++p) {
                    const float s = a[p] + tr[p][c];
                    if (s > best) { best = s; arg = p; }
                }
                mpack |= (unsigned int)arg << (3 * c);
                na[c] = best + pl[t * C_ + c];
            }
            bpk[t] = mpack;
            #pragma unroll
            for (int c = 0; c < C_; ++c) a[c] = na[c];
        }
    }

    if (lane == 63) {
        float best = a[0];
        int arg = 0;
        #pragma unroll
        for (int p = 1; p < C_; ++p)
            if (a[p] > best) { best = a[p]; arg = p; }
        s_last = arg;
    }
    if (lane == 0) bpk[0] = 0;
    __syncthreads();

    const int last = s_last;

    unsigned int g = 0u | (1u << 3) | (2u << 6) | (3u << 9) | (4u << 12);
    #pragma unroll
    for (int j = 7; j >= 0; --j) {
        const int t = 8 * lane + j;
        if (t >= 1) {
            const unsigned int m = bpk[t];
            unsigned int ng = 0;
            #pragma unroll
            for (int x = 0; x < C_; ++x) {
                const unsigned int gx = (g >> (3 * x)) & 7u;
                ng |= ((m >> (3 * gx)) & 7u) << (3 * x);
            }
            g = ng;
        }
    }
    gseg[lane] = g;
    __syncthreads();

    if (lane == 0) {
        int cur = last;
        for (int l = 63; l >= 0; --l) {
            bt[l] = cur;
            cur = (int)((gseg[l] >> (3 * cur)) & 7u);
        }
        seqlen[b] = (float)mcnt;
    }
    __syncthreads();

    {
        int tag = bt[lane];
        const int t0 = 8 * lane;
        dec_s[t0 + 7] = tag;
        #pragma unroll
        for (int t = t0 + 7; t >= t0 + 1; --t) {
            tag = (int)((bpk[t] >> (3 * tag)) & 7u);
            dec_s[t - 1] = tag;
        }
    }
    __syncthreads();

    float* db = decoded + b * S_;
    for (int i = lane; i < S_; i += 64) db[i] = (float)dec_s[i];
}

// =========================================================================
extern "C" void kernel_launch(void* const* d_in, const int* in_sizes, int n_in,
                              void* d_out, int out_size, void* d_ws, size_t ws_size,
                              hipStream_t stream) {
    const float* hs    = (const float*)d_in[0];
    const int*   mask  = (const int*)  d_in[1];
    const float* W1    = (const float*)d_in[2];
    const float* b1    = (const float*)d_in[3];
    const float* W2    = (const float*)d_in[4];
    const float* b2    = (const float*)d_in[5];
    const float* chain = (const float*)d_in[6];
    const float* lb    = (const float*)d_in[7];
    const float* rb    = (const float*)d_in[8];

    float* out      = (float*)d_out;
    float* decoded  = out;
    float* pot      = out + M_;
    float* seq      = out + M_ + M_ * C_;
    float* chainout = seq + B_;

    const size_t need_w1 = (size_t)W1T_ELEMS * sizeof(unsigned short);   // 1.18 MB

    if (ws_size >= need_w1) {
        unsigned short* w1t = (unsigned short*)d_ws;
        dim3 pgrid(H_ / 32, D_ / 32);
        prep_w1_kernel<<<pgrid, 256, 0, stream>>>(W1, w1t);
        gemm_fulln_kernel<<<M_ / 64, 512, 0, stream>>>(
            hs, w1t, b1, W2, b2, lb, rb, pot);
    } else {
        const int PI_BLOCKS = (M_ * C_ + 255) / 256;
        init_pot_kernel<<<PI_BLOCKS, 256, 0, stream>>>(b2, lb, rb, pot);
        dim3 grid(H_ / 128, M_ / 128);
        gemm_relu_pot_kernel<<<grid, 256, 0, stream>>>(hs, W1, b1, W2, pot);
    }

    viterbi_kernel<<<B_, 64, 0, stream>>>(pot, chain, mask, decoded, seq, chainout);
}